// Round 1
// baseline (113.395 us; speedup 1.0000x reference)
//
#include <hip/hip_runtime.h>
#include <math.h>

#define EPS 1e-12f

typedef float        f32x4 __attribute__((ext_vector_type(4)));
typedef unsigned int u32x4 __attribute__((ext_vector_type(4)));

// ---------------------------------------------------------------------------
// Pass 1: per-row L2 norm + maxabs; quantize row to int8 with per-row scale.
// 8 lanes per row, each lane owns 4 float4s (16 of 128 elems).
//   - 3 shuffle-reduce levels (vs 5 with 32 lanes/row): 6 DS ops/thread, and
//     4x fewer threads -> ~6.7x fewer total DS-pipe ops than the 32-lane form.
//   - nontemporal loads: h is read exactly once; keep L2 clean for hq/scale
//     which pass 2 re-reads.
// q = round(127 * x / maxabs_raw) — the 1/||x|| factor cancels, so we quantize
// raw values and fold the norm into the stored scale.
// Row layout permutation (lane-major 16B chunks) is identical for every row,
// and the dot product is permutation-invariant, so pass 2 needs no changes.
// ---------------------------------------------------------------------------
__device__ inline void accum_sq_max(f32x4 v, float& ss, float& ma) {
    ss += v[0] * v[0] + v[1] * v[1] + v[2] * v[2] + v[3] * v[3];
    ma = fmaxf(ma, fmaxf(fmaxf(fabsf(v[0]), fabsf(v[1])),
                         fmaxf(fabsf(v[2]), fabsf(v[3]))));
}

__device__ inline unsigned int pack4(f32x4 v, float qs) {
    int qx = __float2int_rn(v[0] * qs);
    int qy = __float2int_rn(v[1] * qs);
    int qz = __float2int_rn(v[2] * qs);
    int qw = __float2int_rn(v[3] * qs);
    return ((unsigned int)qx & 0xffu)
         | (((unsigned int)qy & 0xffu) << 8)
         | (((unsigned int)qz & 0xffu) << 16)
         | (((unsigned int)qw & 0xffu) << 24);
}

__global__ void __launch_bounds__(256) norm_q8_kernel(const float* __restrict__ h,
                                                      u32x4* __restrict__ hq,
                                                      float* __restrict__ scale,
                                                      int N) {
    int tid  = blockIdx.x * blockDim.x + threadIdx.x;
    int row  = tid >> 3;               // 8 lanes per row
    int lane = threadIdx.x & 7;
    if (row >= N) return;
    const f32x4* rp = (const f32x4*)(h + (size_t)row * 128);
    // 4 independent 16B loads per lane; 8 lanes cover the 512B row.
    f32x4 v0 = __builtin_nontemporal_load(rp + lane);
    f32x4 v1 = __builtin_nontemporal_load(rp + lane + 8);
    f32x4 v2 = __builtin_nontemporal_load(rp + lane + 16);
    f32x4 v3 = __builtin_nontemporal_load(rp + lane + 24);
    float ss = 0.0f, ma = 0.0f;
    accum_sq_max(v0, ss, ma);
    accum_sq_max(v1, ss, ma);
    accum_sq_max(v2, ss, ma);
    accum_sq_max(v3, ss, ma);
    // xor offsets 4,2,1 stay inside this row's 8-lane group
    #pragma unroll
    for (int off = 4; off > 0; off >>= 1) {
        ss += __shfl_xor(ss, off, 64);
        ma = fmaxf(ma, __shfl_xor(ma, off, 64));
    }
    float r  = 1.0f / fmaxf(sqrtf(ss), EPS);   // 1/||x||
    float qs = 127.0f / fmaxf(ma, 1e-30f);     // quant multiplier on raw x
    u32x4 P;
    P[0] = pack4(v0, qs);
    P[1] = pack4(v1, qs);
    P[2] = pack4(v2, qs);
    P[3] = pack4(v3, qs);
    hq[(size_t)row * 8 + lane] = P;            // cached store: pass 2 re-reads
    if (lane == 0)
        scale[row] = ma * r * (1.0f / 127.0f); // maxabs of NORMALIZED row / 127
}

// int8x4 dot-accumulate
__device__ inline int dot4i8(unsigned int a, unsigned int b, int c) {
#if __has_builtin(__builtin_amdgcn_sdot4)
    return __builtin_amdgcn_sdot4((int)a, (int)b, c, false);
#else
    c += (int)(signed char)(a)       * (int)(signed char)(b);
    c += (int)(signed char)(a >> 8)  * (int)(signed char)(b >> 8);
    c += (int)(signed char)(a >> 16) * (int)(signed char)(b >> 16);
    c += (int)(signed char)(a >> 24) * (int)(signed char)(b >> 24);
    return c;
#endif
}

__device__ inline int dot16(u32x4 a, u32x4 b, int c) {
    c = dot4i8(a[0], b[0], c);
    c = dot4i8(a[1], b[1], c);
    c = dot4i8(a[2], b[2], c);
    c = dot4i8(a[3], b[3], c);
    return c;
}

// ---------------------------------------------------------------------------
// Pass 2: per-edge dot on int8 rows. 4 lanes/edge; each lane loads 2 u32x4
// per row (row = 128 B = one aligned L2 line). Integer accumulate
// (max |sum| ~2.1e6, fits int32), then out = acc * scale[s] * scale[d].
// Load order: indices -> row gathers (longest latency, needed first) ->
// scales (only needed after dot + 2 shuffles). Nontemporal out store: out is
// never re-read; don't evict hq rows from L2.
// ---------------------------------------------------------------------------
__global__ void __launch_bounds__(256) edge_q8_kernel(const u32x4* __restrict__ hq,
                                                      const int* __restrict__ src,
                                                      const int* __restrict__ dst,
                                                      const float* __restrict__ scale,
                                                      float* __restrict__ out,
                                                      int E) {
    int tid = blockIdx.x * blockDim.x + threadIdx.x;
    int e   = tid >> 2;               // 4 lanes per edge
    int sub = threadIdx.x & 3;
    if (e >= E) return;
    int s = src[e];
    int d = dst[e];
    const u32x4* rs = hq + (size_t)s * 8;
    const u32x4* rd = hq + (size_t)d * 8;
    // issue all row gathers back-to-back
    u32x4 a0 = rs[sub];
    u32x4 a1 = rs[sub + 4];
    u32x4 b0 = rd[sub];
    u32x4 b1 = rd[sub + 4];
    float sa = scale[s];
    float sd = scale[d];
    int acc = 0;
    acc = dot16(a0, b0, acc);
    acc = dot16(a1, b1, acc);
    // reduce across the 4-lane group
    acc += __shfl_xor(acc, 2, 64);
    acc += __shfl_xor(acc, 1, 64);
    if (sub == 0)
        __builtin_nontemporal_store((float)acc * sa * sd, out + e);
}

// ---- Fallback path (ws too small): f32 kernels ----
__global__ void __launch_bounds__(256) rnorm_kernel(const float* __restrict__ h,
                                                    float* __restrict__ rnorm,
                                                    int N) {
    int row  = (blockIdx.x * blockDim.x + threadIdx.x) >> 6;
    int lane = threadIdx.x & 63;
    if (row >= N) return;
    const float2* rp = (const float2*)(h + (size_t)row * 128);
    float2 v = rp[lane];
    float s = v.x * v.x + v.y * v.y;
    #pragma unroll
    for (int off = 32; off > 0; off >>= 1)
        s += __shfl_xor(s, off, 64);
    if (lane == 0)
        rnorm[row] = 1.0f / fmaxf(sqrtf(s), EPS);
}

__global__ void __launch_bounds__(256) edge_f32_kernel(const float* __restrict__ h,
                                                       const int* __restrict__ src,
                                                       const int* __restrict__ dst,
                                                       const float* __restrict__ rnorm,
                                                       float* __restrict__ out,
                                                       int E) {
    int tid = blockIdx.x * blockDim.x + threadIdx.x;
    int e   = tid >> 5;
    int sub = threadIdx.x & 31;
    if (e >= E) return;
    int s = src[e];
    int d = dst[e];
    const float4* rs = (const float4*)(h + (size_t)s * 128);
    const float4* rd = (const float4*)(h + (size_t)d * 128);
    float4 a = rs[sub];
    float4 b = rd[sub];
    float p = a.x * b.x + a.y * b.y + a.z * b.z + a.w * b.w;
    #pragma unroll
    for (int off = 16; off > 0; off >>= 1)
        p += __shfl_xor(p, off, 64);
    if (sub == 0)
        out[e] = p * rnorm[s] * rnorm[d];
}

extern "C" void kernel_launch(void* const* d_in, const int* in_sizes, int n_in,
                              void* d_out, int out_size, void* d_ws, size_t ws_size,
                              hipStream_t stream) {
    const float* h   = (const float*)d_in[0];
    const int*   src = (const int*)d_in[1];
    const int*   dst = (const int*)d_in[2];
    float*       out = (float*)d_out;

    const int N = in_sizes[0] / 128;   // 100000
    const int E = in_sizes[1];         // 640000

    size_t hq_bytes    = (size_t)N * 128;        // 12.8 MB int8 rows
    size_t scale_bytes = (size_t)N * sizeof(float);

    if (ws_size >= hq_bytes + scale_bytes) {
        u32x4* hq    = (u32x4*)d_ws;
        float* scale = (float*)((char*)d_ws + hq_bytes);
        {
            long long threads = (long long)N * 8;    // 8 lanes per row
            int grid = (int)((threads + 255) / 256);
            norm_q8_kernel<<<grid, 256, 0, stream>>>(h, hq, scale, N);
        }
        {
            long long threads = (long long)E * 4;    // 4 lanes per edge
            int grid = (int)((threads + 255) / 256);
            edge_q8_kernel<<<grid, 256, 0, stream>>>(hq, src, dst, scale, out, E);
        }
    } else {
        float* rnorm = (float*)d_ws;                 // N floats
        {
            int grid = (N * 64 + 255) / 256;
            rnorm_kernel<<<grid, 256, 0, stream>>>(h, rnorm, N);
        }
        {
            int grid = (E * 32 + 255) / 256;
            edge_f32_kernel<<<grid, 256, 0, stream>>>(h, src, dst, rnorm, out, E);
        }
    }
}